// Round 8
// baseline (185.616 us; speedup 1.0000x reference)
//
#include <hip/hip_runtime.h>

#define NC 14
#define DIM 96
#define NV (DIM*DIM*DIM)       // 884736
#define NV4 (NV/4)             // 221184
// padded mask volume: [ph 98][pw 98][pd 112], voxel (h,w,d) -> (h+1, w+1, d+8)
#define WS2 112
#define HS2 (112*98)           // 10976
#define PADV (112*98*98)       // 1075648 elements per batch
#define SLABB ((size_t)PADV*2*2)   // bytes for 2 batches of ushort = 4302592

typedef float f4 __attribute__((ext_vector_type(4)));

// ---- Kernel A: argmax over classes, 4 voxels/thread -> bitmask ushort4 ----
// outputs_T (99MB) stays CACHED: it fits Infinity Cache and is reused across
// graph replays (NT-streamed preds don't evict it).
__global__ void __launch_bounds__(256)
argmax_bit_kernel(const float* __restrict__ outT, unsigned short* __restrict__ bm) {
    int tid = blockIdx.x * 256 + threadIdx.x;       // < 2*NV4 exactly
    int b = tid >= NV4;
    int q = tid - b * NV4;
    int v4 = q * 4;
    const float* po = outT + (size_t)b * NC * NV + v4;
    f4 best = *(const f4*)po;
    int b0 = 0, b1 = 0, b2 = 0, b3 = 0;
#pragma unroll
    for (int c = 1; c < NC; ++c) {
        f4 v = *(const f4*)(po + (size_t)c * NV);
        if (v.x > best.x) { best.x = v.x; b0 = c; }
        if (v.y > best.y) { best.y = v.y; b1 = c; }
        if (v.z > best.z) { best.z = v.z; b2 = c; }
        if (v.w > best.w) { best.w = v.w; b3 = c; }
    }
    int d = v4 % DIM;
    int t1 = v4 / DIM;
    int w = t1 % DIM;
    int h = t1 / DIM;
    ushort4 bits;
    bits.x = (unsigned short)(1u << b0);
    bits.y = (unsigned short)(1u << b1);
    bits.z = (unsigned short)(1u << b2);
    bits.w = (unsigned short)(1u << b3);
    *(ushort4*)(bm + (size_t)b * PADV + (h + 1) * HS2 + (w + 1) * WS2 + (d + 8)) = bits;
}

// ---- Kernel B: fused (w,d) 3x3 window-OR per h-slice, LDS-staged ----
// One block per (batch, h) slice. Stages the 98x112 bm slice into LDS with
// zeroed halo, computes OR over the 3x3 (w,d) window, writes wm IN PLACE
// (wm aliases bm: slice-local dependency, fully staged before stores).
// Block 0 also zeroes the 4KB accumulator (replaces hipMemsetAsync).
__global__ void __launch_bounds__(256)
or_dw_kernel(unsigned short* __restrict__ mask, float* __restrict__ acc) {
    if (blockIdx.x == 0 && threadIdx.x < 64) acc[threadIdx.x * 16] = 0.f;

    const int b = blockIdx.x & 1;
    const int ph = (blockIdx.x >> 1) + 1;           // 1..96
    unsigned short* slice = mask + (size_t)b * PADV + ph * HS2;

    __shared__ unsigned short tile[98][WS2];        // 21,952 B
    // zero-init (halo rows/cols must be 0; pads are never written globally)
    for (int i = threadIdx.x; i < 98 * WS2 / 2; i += 256)
        ((unsigned*)tile)[i] = 0u;
    __syncthreads();
    // load valid region: pw 1..96, pd 8..103 (12 uint4 per row)
    for (int i = threadIdx.x; i < 96 * 12; i += 256) {
        int row = 1 + i / 12;
        int pd0 = 8 + (i % 12) * 8;
        *(uint4*)&tile[row][pd0] = *(const uint4*)(slice + row * WS2 + pd0);
    }
    __syncthreads();

    // compute: 96 rows x 12 chunks of 8
    for (int i = threadIdx.x; i < 96 * 12; i += 256) {
        int pw = 1 + i / 12;
        int pd0 = 8 + (i % 12) * 8;
        // w-OR of the three rows first (OR is associative/commutative)
        uint4 A = *(const uint4*)&tile[pw - 1][pd0];
        uint4 B = *(const uint4*)&tile[pw][pd0];
        uint4 C = *(const uint4*)&tile[pw + 1][pd0];
        unsigned lft = (unsigned)tile[pw - 1][pd0 - 1] | (unsigned)tile[pw][pd0 - 1] |
                       (unsigned)tile[pw + 1][pd0 - 1];
        unsigned rgt = (unsigned)tile[pw - 1][pd0 + 8] | (unsigned)tile[pw][pd0 + 8] |
                       (unsigned)tile[pw + 1][pd0 + 8];
        uint4 W;
        W.x = A.x | B.x | C.x;
        W.y = A.y | B.y | C.y;
        W.z = A.z | B.z | C.z;
        W.w = A.w | B.w | C.w;
        unsigned x[10];
        x[0] = lft;
        x[1] = W.x & 0xFFFFu; x[2] = W.x >> 16;
        x[3] = W.y & 0xFFFFu; x[4] = W.y >> 16;
        x[5] = W.z & 0xFFFFu; x[6] = W.z >> 16;
        x[7] = W.w & 0xFFFFu; x[8] = W.w >> 16;
        x[9] = rgt;
        unsigned r[8];
#pragma unroll
        for (int j = 0; j < 8; ++j) r[j] = x[j] | x[j + 1] | x[j + 2];
        uint4 out;
        out.x = r[0] | (r[1] << 16);
        out.y = r[2] | (r[3] << 16);
        out.z = r[4] | (r[5] << 16);
        out.w = r[6] | (r[7] << 16);
        *(uint4*)(slice + pw * WS2 + pd0) = out;    // in-place: slice staged
    }
}

// ---- Kernel C: h-OR (edge-clamped) + KL + accumulation, 4 voxels/thread ----
// preds_S/preds_T (198MB) streamed NON-TEMPORAL: they can't fit L3 alongside
// outputs_T; bypassing stops L3 thrash. launch_bounds(.,8) caps VGPR at 64
// -> 8 waves/SIMD.
__global__ void __launch_bounds__(256, 8)
boundary_kl_kernel(const float* __restrict__ pS, const float* __restrict__ pT,
                   const unsigned short* __restrict__ wm,
                   float* __restrict__ acc) {
    const int b = blockIdx.x & 1;
    int tid4 = (blockIdx.x >> 1) * 256 + threadIdx.x;    // < NV4 exactly
    int v4 = tid4 * 4;
    int d = v4 % DIM;                                    // multiple of 4
    int t1 = v4 / DIM;
    int w = t1 % DIM;
    int h = t1 / DIM;

    const float* sS = pS + (size_t)b * NC * NV + v4;
    const float* sT = pT + (size_t)b * NC * NV + v4;
    const unsigned short* w0 = wm + (size_t)b * PADV;

    int off = (h + 1) * HS2 + (w + 1) * WS2 + (d + 8);
    ushort4 m1 = *(const ushort4*)(w0 + off);
    ushort4 m0 = {0, 0, 0, 0}, m2 = {0, 0, 0, 0};
    if (h > 0)  m0 = *(const ushort4*)(w0 + off - HS2);  // h-1 slab (0 at edge)
    if (h < 95) m2 = *(const ushort4*)(w0 + off + HS2);  // h+1 slab

    f4 seS = {0, 0, 0, 0}, seT = {0, 0, 0, 0}, dot = {0, 0, 0, 0};
#pragma unroll
    for (int c = 0; c < NC; ++c) {
        f4 vs = __builtin_nontemporal_load((const f4*)(sS + (size_t)c * NV));
        f4 vt = __builtin_nontemporal_load((const f4*)(sT + (size_t)c * NV));
        float e;
        seS.x += __expf(vs.x); e = __expf(vt.x); seT.x += e; dot.x += e * (vt.x - vs.x);
        seS.y += __expf(vs.y); e = __expf(vt.y); seT.y += e; dot.y += e * (vt.y - vs.y);
        seS.z += __expf(vs.z); e = __expf(vt.z); seT.z += e; dot.z += e * (vt.z - vs.z);
        seS.w += __expf(vs.w); e = __expf(vt.w); seT.w += e; dot.w += e * (vt.w - vs.w);
    }
    float pk[4];
    pk[0] = dot.x / seT.x + __logf(seS.x) - __logf(seT.x);
    pk[1] = dot.y / seT.y + __logf(seS.y) - __logf(seT.y);
    pk[2] = dot.z / seT.z + __logf(seS.z) - __logf(seT.z);
    pk[3] = dot.w / seT.w + __logf(seS.w) - __logf(seT.w);

    unsigned mk[4];
    mk[0] = (unsigned)(m0.x | m1.x | m2.x);
    mk[1] = (unsigned)(m0.y | m1.y | m2.y);
    mk[2] = (unsigned)(m0.z | m1.z | m2.z);
    mk[3] = (unsigned)(m0.w | m1.w | m2.w);

    bool hwint = ((unsigned)(h - 1) <= 93u) && ((unsigned)(w - 1) <= 93u);
    float num[NC], cnt[NC];
#pragma unroll
    for (int c = 0; c < NC; ++c) { num[c] = 0.f; cnt[c] = 0.f; }
#pragma unroll
    for (int j = 0; j < 4; ++j) {
        unsigned m = mk[j];
        // fully-interior uniform 3x3x3 window -> box-sum==27 -> not boundary
        if (hwint && ((unsigned)(d + j - 1) <= 93u) && (m & (m - 1)) == 0u) m = 0u;
        float p = pk[j];
#pragma unroll
        for (int c = 0; c < NC; ++c) {
            float hit = (float)((m >> c) & 1u);
            num[c] = fmaf(hit, p, num[c]);
            cnt[c] += hit;
        }
    }

    // wave shfl reduction -> LDS -> global atomics (spread slots, 64B apart)
    __shared__ float snum[NC], scnt[NC];
    if (threadIdx.x < NC) { snum[threadIdx.x] = 0.f; scnt[threadIdx.x] = 0.f; }
    __syncthreads();
    int lane = threadIdx.x & 63;
#pragma unroll
    for (int c = 0; c < NC; ++c) {
        float s = num[c], n = cnt[c];
#pragma unroll
        for (int o = 32; o; o >>= 1) {
            s += __shfl_xor(s, o);
            n += __shfl_xor(n, o);
        }
        if (lane == 0) {
            atomicAdd(&snum[c], s);
            atomicAdd(&scnt[c], n);
        }
    }
    __syncthreads();
    if (threadIdx.x < NC) {
        atomicAdd(&acc[(b * NC + threadIdx.x) * 16], snum[threadIdx.x]);
        atomicAdd(&acc[(32 + b * NC + threadIdx.x) * 16], scnt[threadIdx.x]);
    }
}

// ---- Kernel D: finalize scalar ----
__global__ void finalize_kernel(const float* __restrict__ acc, float* __restrict__ out) {
    if (threadIdx.x == 0 && blockIdx.x == 0) {
        float s = 0.f;
        for (int i = 0; i < 2 * NC; ++i) {
            float n = acc[(32 + i) * 16];
            if (n > 0.f) s += acc[i * 16] / ((float)NC * n);
        }
        out[0] = s;
    }
}

extern "C" void kernel_launch(void* const* d_in, const int* in_sizes, int n_in,
                              void* d_out, int out_size, void* d_ws, size_t ws_size,
                              hipStream_t stream) {
    const float* preds_S = (const float*)d_in[0];
    const float* preds_T = (const float*)d_in[1];
    const float* outputs_T = (const float*)d_in[2];

    // ws layout: [4KB acc][mask slab: bm, rewritten in place to wm]
    // No memset: edge-clamped consumers never read unwritten cells; acc is
    // zeroed inside or_dw (block 0) each call.
    char* ws = (char*)d_ws;
    float* acc = (float*)ws;
    unsigned short* mask = (unsigned short*)(ws + 4096);

    argmax_bit_kernel<<<(2 * NV4) / 256, 256, 0, stream>>>(outputs_T, mask);
    or_dw_kernel<<<192, 256, 0, stream>>>(mask, acc);
    boundary_kl_kernel<<<2 * (NV4 / 256), 256, 0, stream>>>(preds_S, preds_T, mask, acc);
    finalize_kernel<<<1, 64, 0, stream>>>(acc, (float*)d_out);
}

// Round 9
// 85.628 us; speedup vs baseline: 2.1677x; 2.1677x over previous
//
#include <hip/hip_runtime.h>

#define NC 14
#define DIM 96
#define NV (DIM*DIM*DIM)       // 884736
#define NV4 (NV/4)             // 221184
// padded mask volume: [ph 98][pw 98][pd 112], voxel (h,w,d) -> (h+1, w+1, d+8)
#define WS2 112
#define HS2 (112*98)           // 10976
#define PADV (112*98*98)       // 1075648 elements per batch

typedef float f4 __attribute__((ext_vector_type(4)));

// ---- Kernel A: argmax over classes, 4 voxels/thread -> bitmask ushort4 ----
// outputs_T (99MB) stays CACHED: it fits Infinity Cache and is reused across
// graph replays (NT-streamed preds don't evict it).
__global__ void __launch_bounds__(256)
argmax_bit_kernel(const float* __restrict__ outT, unsigned short* __restrict__ bm) {
    int tid = blockIdx.x * 256 + threadIdx.x;       // < 2*NV4 exactly
    int b = tid >= NV4;
    int q = tid - b * NV4;
    int v4 = q * 4;
    const float* po = outT + (size_t)b * NC * NV + v4;
    f4 best = *(const f4*)po;
    int b0 = 0, b1 = 0, b2 = 0, b3 = 0;
#pragma unroll
    for (int c = 1; c < NC; ++c) {
        f4 v = *(const f4*)(po + (size_t)c * NV);
        if (v.x > best.x) { best.x = v.x; b0 = c; }
        if (v.y > best.y) { best.y = v.y; b1 = c; }
        if (v.z > best.z) { best.z = v.z; b2 = c; }
        if (v.w > best.w) { best.w = v.w; b3 = c; }
    }
    int d = v4 % DIM;
    int t1 = v4 / DIM;
    int w = t1 % DIM;
    int h = t1 / DIM;
    ushort4 bits;
    bits.x = (unsigned short)(1u << b0);
    bits.y = (unsigned short)(1u << b1);
    bits.z = (unsigned short)(1u << b2);
    bits.w = (unsigned short)(1u << b3);
    *(ushort4*)(bm + (size_t)b * PADV + (h + 1) * HS2 + (w + 1) * WS2 + (d + 8)) = bits;
}

// ---- Kernel B: fused (w,d) 3x3 window-OR per h-slice, LDS-staged ----
// One block per (batch, h) slice. Stages the 98x112 bm slice into LDS with
// zeroed halo, computes OR over the 3x3 (w,d) window, writes back IN PLACE
// (slice-local dependency, fully staged before stores).
// Block 0 also zeroes the 4KB accumulator (replaces hipMemsetAsync).
__global__ void __launch_bounds__(256)
or_dw_kernel(unsigned short* __restrict__ mask, float* __restrict__ acc) {
    if (blockIdx.x == 0 && threadIdx.x < 64) acc[threadIdx.x * 16] = 0.f;

    const int b = blockIdx.x & 1;
    const int ph = (blockIdx.x >> 1) + 1;           // 1..96
    unsigned short* slice = mask + (size_t)b * PADV + ph * HS2;

    __shared__ unsigned short tile[98][WS2];        // 21,952 B
    // zero-init (halo rows/cols must be 0; pads are never written globally)
    for (int i = threadIdx.x; i < 98 * WS2 / 2; i += 256)
        ((unsigned*)tile)[i] = 0u;
    __syncthreads();
    // load valid region: pw 1..96, pd 8..103 (12 uint4 per row)
    for (int i = threadIdx.x; i < 96 * 12; i += 256) {
        int row = 1 + i / 12;
        int pd0 = 8 + (i % 12) * 8;
        *(uint4*)&tile[row][pd0] = *(const uint4*)(slice + row * WS2 + pd0);
    }
    __syncthreads();

    // compute: 96 rows x 12 chunks of 8
    for (int i = threadIdx.x; i < 96 * 12; i += 256) {
        int pw = 1 + i / 12;
        int pd0 = 8 + (i % 12) * 8;
        // w-OR of the three rows first (OR is associative/commutative)
        uint4 A = *(const uint4*)&tile[pw - 1][pd0];
        uint4 B = *(const uint4*)&tile[pw][pd0];
        uint4 C = *(const uint4*)&tile[pw + 1][pd0];
        unsigned lft = (unsigned)tile[pw - 1][pd0 - 1] | (unsigned)tile[pw][pd0 - 1] |
                       (unsigned)tile[pw + 1][pd0 - 1];
        unsigned rgt = (unsigned)tile[pw - 1][pd0 + 8] | (unsigned)tile[pw][pd0 + 8] |
                       (unsigned)tile[pw + 1][pd0 + 8];
        uint4 W;
        W.x = A.x | B.x | C.x;
        W.y = A.y | B.y | C.y;
        W.z = A.z | B.z | C.z;
        W.w = A.w | B.w | C.w;
        unsigned x[10];
        x[0] = lft;
        x[1] = W.x & 0xFFFFu; x[2] = W.x >> 16;
        x[3] = W.y & 0xFFFFu; x[4] = W.y >> 16;
        x[5] = W.z & 0xFFFFu; x[6] = W.z >> 16;
        x[7] = W.w & 0xFFFFu; x[8] = W.w >> 16;
        x[9] = rgt;
        unsigned r[8];
#pragma unroll
        for (int j = 0; j < 8; ++j) r[j] = x[j] | x[j + 1] | x[j + 2];
        uint4 out;
        out.x = r[0] | (r[1] << 16);
        out.y = r[2] | (r[3] << 16);
        out.z = r[4] | (r[5] << 16);
        out.w = r[6] | (r[7] << 16);
        *(uint4*)(slice + pw * WS2 + pd0) = out;    // in-place: slice staged
    }
}

// ---- Kernel C: h-OR (edge-clamped) + KL + accumulation, 4 voxels/thread ----
// preds_S/preds_T (198MB) streamed NON-TEMPORAL: they can't fit L3 alongside
// outputs_T; bypassing stops L3 thrash and keeps the HBM path clean.
// NOTE: natural VGPR need is ~68; forcing 8 waves/SIMD (<=64 VGPR) spills to
// scratch (round 8: WRITE_SIZE 0.3->214MB, 2x slower). Keep natural bounds.
__global__ void __launch_bounds__(256)
boundary_kl_kernel(const float* __restrict__ pS, const float* __restrict__ pT,
                   const unsigned short* __restrict__ wm,
                   float* __restrict__ acc) {
    const int b = blockIdx.x & 1;
    int tid4 = (blockIdx.x >> 1) * 256 + threadIdx.x;    // < NV4 exactly
    int v4 = tid4 * 4;
    int d = v4 % DIM;                                    // multiple of 4
    int t1 = v4 / DIM;
    int w = t1 % DIM;
    int h = t1 / DIM;

    const float* sS = pS + (size_t)b * NC * NV + v4;
    const float* sT = pT + (size_t)b * NC * NV + v4;
    const unsigned short* w0 = wm + (size_t)b * PADV;

    int off = (h + 1) * HS2 + (w + 1) * WS2 + (d + 8);
    ushort4 m1 = *(const ushort4*)(w0 + off);
    ushort4 m0 = {0, 0, 0, 0}, m2 = {0, 0, 0, 0};
    if (h > 0)  m0 = *(const ushort4*)(w0 + off - HS2);  // h-1 slab (0 at edge)
    if (h < 95) m2 = *(const ushort4*)(w0 + off + HS2);  // h+1 slab

    f4 seS = {0, 0, 0, 0}, seT = {0, 0, 0, 0}, dot = {0, 0, 0, 0};
#pragma unroll
    for (int c = 0; c < NC; ++c) {
        f4 vs = __builtin_nontemporal_load((const f4*)(sS + (size_t)c * NV));
        f4 vt = __builtin_nontemporal_load((const f4*)(sT + (size_t)c * NV));
        float e;
        seS.x += __expf(vs.x); e = __expf(vt.x); seT.x += e; dot.x += e * (vt.x - vs.x);
        seS.y += __expf(vs.y); e = __expf(vt.y); seT.y += e; dot.y += e * (vt.y - vs.y);
        seS.z += __expf(vs.z); e = __expf(vt.z); seT.z += e; dot.z += e * (vt.z - vs.z);
        seS.w += __expf(vs.w); e = __expf(vt.w); seT.w += e; dot.w += e * (vt.w - vs.w);
    }
    float pk[4];
    pk[0] = dot.x / seT.x + __logf(seS.x) - __logf(seT.x);
    pk[1] = dot.y / seT.y + __logf(seS.y) - __logf(seT.y);
    pk[2] = dot.z / seT.z + __logf(seS.z) - __logf(seT.z);
    pk[3] = dot.w / seT.w + __logf(seS.w) - __logf(seT.w);

    unsigned mk[4];
    mk[0] = (unsigned)(m0.x | m1.x | m2.x);
    mk[1] = (unsigned)(m0.y | m1.y | m2.y);
    mk[2] = (unsigned)(m0.z | m1.z | m2.z);
    mk[3] = (unsigned)(m0.w | m1.w | m2.w);

    bool hwint = ((unsigned)(h - 1) <= 93u) && ((unsigned)(w - 1) <= 93u);
    float num[NC], cnt[NC];
#pragma unroll
    for (int c = 0; c < NC; ++c) { num[c] = 0.f; cnt[c] = 0.f; }
#pragma unroll
    for (int j = 0; j < 4; ++j) {
        unsigned m = mk[j];
        // fully-interior uniform 3x3x3 window -> box-sum==27 -> not boundary
        if (hwint && ((unsigned)(d + j - 1) <= 93u) && (m & (m - 1)) == 0u) m = 0u;
        float p = pk[j];
#pragma unroll
        for (int c = 0; c < NC; ++c) {
            float hit = (float)((m >> c) & 1u);
            num[c] = fmaf(hit, p, num[c]);
            cnt[c] += hit;
        }
    }

    // wave shfl reduction -> LDS -> global atomics (spread slots, 64B apart)
    __shared__ float snum[NC], scnt[NC];
    if (threadIdx.x < NC) { snum[threadIdx.x] = 0.f; scnt[threadIdx.x] = 0.f; }
    __syncthreads();
    int lane = threadIdx.x & 63;
#pragma unroll
    for (int c = 0; c < NC; ++c) {
        float s = num[c], n = cnt[c];
#pragma unroll
        for (int o = 32; o; o >>= 1) {
            s += __shfl_xor(s, o);
            n += __shfl_xor(n, o);
        }
        if (lane == 0) {
            atomicAdd(&snum[c], s);
            atomicAdd(&scnt[c], n);
        }
    }
    __syncthreads();
    if (threadIdx.x < NC) {
        atomicAdd(&acc[(b * NC + threadIdx.x) * 16], snum[threadIdx.x]);
        atomicAdd(&acc[(32 + b * NC + threadIdx.x) * 16], scnt[threadIdx.x]);
    }
}

// ---- Kernel D: finalize scalar ----
__global__ void finalize_kernel(const float* __restrict__ acc, float* __restrict__ out) {
    if (threadIdx.x == 0 && blockIdx.x == 0) {
        float s = 0.f;
        for (int i = 0; i < 2 * NC; ++i) {
            float n = acc[(32 + i) * 16];
            if (n > 0.f) s += acc[i * 16] / ((float)NC * n);
        }
        out[0] = s;
    }
}

extern "C" void kernel_launch(void* const* d_in, const int* in_sizes, int n_in,
                              void* d_out, int out_size, void* d_ws, size_t ws_size,
                              hipStream_t stream) {
    const float* preds_S = (const float*)d_in[0];
    const float* preds_T = (const float*)d_in[1];
    const float* outputs_T = (const float*)d_in[2];

    // ws layout: [4KB acc][mask slab, rewritten in place by or_dw]
    // No memset: edge-clamped consumers never read unwritten cells; acc is
    // zeroed inside or_dw (block 0) each call.
    char* ws = (char*)d_ws;
    float* acc = (float*)ws;
    unsigned short* mask = (unsigned short*)(ws + 4096);

    argmax_bit_kernel<<<(2 * NV4) / 256, 256, 0, stream>>>(outputs_T, mask);
    or_dw_kernel<<<192, 256, 0, stream>>>(mask, acc);
    boundary_kl_kernel<<<2 * (NV4 / 256), 256, 0, stream>>>(preds_S, preds_T, mask, acc);
    finalize_kernel<<<1, 64, 0, stream>>>(acc, (float*)d_out);
}